// Round 5
// baseline (271126.562 us; speedup 1.0000x reference)
//
#include <hip/hip_runtime.h>
#include <hip/hip_bf16.h>

// GraphConvLayer: out = relu(A_norm @ (X@W + b))
// Reassociated: Y = A@X (sparse, ~22.5 nnz/row), out = relu(Y@W + rowsum(A)[n]*b[d])
// x: [1024,543,256] f32; W: [256,256] f32; b: [256]; A: [543,543] f32; out: [1024,543,256] f32
//
// R5: 64 rows/block (9 blocks/bt). x streamed once/block through LDS as f32 in
// 64-row chunks (plain float4 copy, no convert). Y = y[8] f32x4/lane (32 VGPR,
// static indexing) -> no scratch. MFMA on bf16 Y (XOR-swz LDS) + prepacked W
// fragments. Epilogue bounces through LDS -> full-cache-line 512B/wave stores.

#define NND    543
#define NROWP  640
#define RPB    64           // rows per block
#define NTILES 9            // blocks per bt
#define CH     64           // x chunk rows (f32 in LDS)
#define NCH    9
#define CAPR   64           // CSR slots per row (mean ~22.5)
#define BTOT   1024
#define GRID   (BTOT*NTILES)   // 9216, %8==0 -> bijective XCD swizzle

typedef __attribute__((ext_vector_type(8))) short short8;
typedef __attribute__((ext_vector_type(4))) float f32x4;

// ---- workspace (bytes) ----
#define WS_ENT 0                          // uint2[640][64] = 327680  {m, f32bits(a)}
#define WS_ST  327680                     // u16[640][12]: st[0..9] chunk offsets, [10] ovf flag
#define WS_RS  343040                     // f32[640] rowsum
#define WS_W   345600                     // bf16 frags [16][8][64][8] = 131072
#define WS_NEED 476672

// ---- LDS (bytes) ----
// [0,65536): x-chunk f32[64][256]; Y-swz bf16[64][512B] overlays [0,32768) after gather
#define L_BNC  65536                      // f32[16][132] = 8448 epilogue bounce
#define L_RS   73984                      // f32[64]
#define L_TOT  74240                      // 74.2KB -> 2 blocks/CU

__device__ __forceinline__ unsigned short f2bf(float f) {   // RNE f32 -> bf16 bits
  unsigned int u = __builtin_bit_cast(unsigned int, f);
  u += 0x7fffu + ((u >> 16) & 1u);
  return (unsigned short)(u >> 16);
}
__device__ __forceinline__ uint2 pack4(const f32x4 v) {
  uint2 u;
  u.x = (unsigned)f2bf(v.x) | ((unsigned)f2bf(v.y) << 16);
  u.y = (unsigned)f2bf(v.z) | ((unsigned)f2bf(v.w) << 16);
  return u;
}

// ---------------- prep: flat CSR + per-64-chunk offsets + rowsum (one wave/row) ----------------
__global__ void prep_csr(const float* __restrict__ A, char* __restrict__ ws) {
  const int wid = (blockIdx.x * blockDim.x + threadIdx.x) >> 6;
  const int lane = threadIdx.x & 63;
  if (wid >= NROWP) return;
  uint2* ep = (uint2*)(ws + WS_ENT) + (size_t)wid * CAPR;
  unsigned short* st = (unsigned short*)(ws + WS_ST) + wid * 12;
  float* rs = (float*)(ws + WS_RS);
  if (wid >= NND) {
    if (lane < 12) st[lane] = 0;
    if (lane == 0) rs[wid] = 0.f;
    return;
  }
  const float* arow = A + (size_t)wid * NND;
  float s = 0.f; int cnt = 0;
  for (int c = 0; c < NCH; ++c) {
    if (lane == 0) st[c] = (unsigned short)cnt;   // nnz with m < c*64
    const int m = c * 64 + lane;
    const float a = (m < NND) ? arow[m] : 0.f;
    s += a;
    const unsigned long long mask = __ballot(a != 0.f);
    if (a != 0.f) {
      const int idx = cnt + (int)__popcll(mask & ((1ull << lane) - 1ull));
      if (idx < CAPR) ep[idx] = make_uint2((unsigned)m, __builtin_bit_cast(unsigned, a));
    }
    cnt += (int)__popcll(mask);
  }
  #pragma unroll
  for (int o = 32; o > 0; o >>= 1) s += __shfl_xor(s, o);
  if (lane == 0) {
    st[9] = (unsigned short)cnt;
    st[10] = (cnt > CAPR) ? (unsigned short)1 : (unsigned short)0;
    st[11] = 0;
    rs[wid] = s;
  }
}

// ---------------- prep: W -> bf16 MFMA B-fragments [g][ks][lane][8] ----------------
__global__ void prep_w(const float* __restrict__ W, char* __restrict__ ws) {
  const int t = blockIdx.x * 256 + threadIdx.x;
  if (t >= 16 * 8 * 64) return;
  const int lane = t & 63, ks = (t >> 6) & 7, g = t >> 9;
  const int krow = (lane >> 4) * 8, col = g * 16 + (lane & 15);
  unsigned short* dst = (unsigned short*)(ws + WS_W) + (size_t)t * 8;
  #pragma unroll
  for (int e = 0; e < 8; e++) dst[e] = f2bf(W[(ks * 32 + krow + e) * 256 + col]);
}

// ---------------- main ----------------
__global__ __launch_bounds__(512, 4)   // 8 waves; VGPR cap 128; LDS 74KB -> 2 blocks/CU
void gcn_main(const float* __restrict__ x, const float* __restrict__ Wm,
              const float* __restrict__ bias, const float* __restrict__ A,
              float* __restrict__ out, const char* __restrict__ ws, int use_ws)
{
  __shared__ __align__(16) char lds[L_TOT];
  float* bnc = (float*)(lds + L_BNC);
  float* rsl = (float*)(lds + L_RS);

  const int tid = threadIdx.x;
  const int w = tid >> 6, lane = tid & 63;
  const int cl = lane & 15, krow = (lane >> 4) * 8;

  // XCD swizzle: the 9 tiles of one bt adjacent on one XCD, marching chunks in phase
  const int p = blockIdx.x;
  const int L = (p & 7) * (GRID / 8) + (p >> 3);
  const int bt = L / NTILES;
  const int tile = L - bt * NTILES;
  const int n0 = tile * RPB;

  const float* xbt = x + (size_t)bt * (NND * 256);
  const uint2* entp = (const uint2*)(ws + WS_ENT);
  const unsigned short* stp = (const unsigned short*)(ws + WS_ST);

  if (tid < RPB) rsl[tid] = use_ws ? ((const float*)(ws + WS_RS))[n0 + tid] : 0.f;

  // ---- gather: Y = A@X; x streamed once through LDS (f32, 9 chunks of 64 rows) ----
  f32x4 y[8];
  #pragma unroll
  for (int i = 0; i < 8; i++) y[i] = (f32x4){0.f, 0.f, 0.f, 0.f};

  for (int c = 0; c < NCH; ++c) {
    const int mbase = c * CH;
    const int rows = min(CH, NND - mbase);
    __syncthreads();                      // previous chunk's gather reads done
    #pragma unroll
    for (int k = 0; k < 8; ++k) {         // stage 64x256 f32, coalesced copy
      const int sl = tid + (k << 9);
      const int row = sl >> 6, f4 = sl & 63;
      if (row < rows)
        *(float4*)(lds + (row << 10) + (f4 << 4)) =
            *(const float4*)(xbt + ((size_t)(mbase + row) << 8) + (f4 << 2));
    }
    __syncthreads();

    auto gatherRow = [&](f32x4& yv, const int n) {
      if (use_ws) {
        const unsigned short* stn = stp + n * 12;
        if (!stn[10]) {
          int j = stn[c];
          const int j1 = stn[c + 1];
          const uint2* ep = entp + (size_t)n * CAPR;
          for (; j + 1 < j1; j += 2) {
            const uint2 e0 = ep[j], e1 = ep[j + 1];
            const f32x4 x0 = *(const f32x4*)(lds + (((int)e0.x - mbase) << 10) + (lane << 4));
            const f32x4 x1 = *(const f32x4*)(lds + (((int)e1.x - mbase) << 10) + (lane << 4));
            yv += __builtin_bit_cast(float, e0.y) * x0;
            yv += __builtin_bit_cast(float, e1.y) * x1;
          }
          if (j < j1) {
            const uint2 e0 = ep[j];
            const f32x4 x0 = *(const f32x4*)(lds + (((int)e0.x - mbase) << 10) + (lane << 4));
            yv += __builtin_bit_cast(float, e0.y) * x0;
          }
          return;
        }
      }
      if (n < NND) {                      // overflow row or no-ws fallback: dense segment scan
        const float* arow = A + (size_t)n * NND + mbase;
        for (int m = 0; m < rows; ++m) {
          const float a = arow[m];
          if (a != 0.f) {
            const f32x4 xv = *(const f32x4*)(lds + (m << 10) + (lane << 4));
            yv += a * xv;
          }
        }
      }
    };
    #pragma unroll
    for (int rr = 0; rr < 8; ++rr) gatherRow(y[rr], n0 + w * 8 + rr);
  }

  if (!use_ws) {                          // fallback rowsums
    __syncthreads();
    for (int r = w; r < RPB; r += 8) {
      const int n = n0 + r;
      float s = 0.f;
      if (n < NND) for (int m = lane; m < NND; m += 64) s += A[(size_t)n * NND + m];
      #pragma unroll
      for (int o = 32; o > 0; o >>= 1) s += __shfl_xor(s, o);
      if (lane == 0) rsl[r] = s;
    }
  }

  // ---- Y -> LDS bf16 [64][256], XOR-swizzled (overlays dead x-chunk buffer) ----
  __syncthreads();
  #pragma unroll
  for (int rr = 0; rr < 8; ++rr) {
    const int r = w * 8 + rr;
    *(uint2*)(lds + r * 512 + ((lane * 8) ^ ((r & 7) << 4))) = pack4(y[rr]);
  }
  __syncthreads();

  // ---- MFMA: out_tile[64 x 256] = relu(Y@W + rs*b); wave w cols w*16 + dt*128 ----
  for (int dt = 0; dt < 2; ++dt) {
    const int d0 = dt * 128 + w * 16 + cl;
    short8 wf[8];
    if (use_ws) {
      const int g = dt * 8 + w;
      #pragma unroll
      for (int ks = 0; ks < 8; ++ks)
        wf[ks] = *(const short8*)(ws + WS_W + (size_t)(((g * 8 + ks) * 64 + lane) << 4));
    } else {
      #pragma unroll
      for (int ks = 0; ks < 8; ++ks) {
        #pragma unroll
        for (int e = 0; e < 8; ++e)
          wf[ks][e] = (short)f2bf(Wm[(ks * 32 + krow + e) * 256 + d0]);
      }
    }
    f32x4 acc[4];
    #pragma unroll
    for (int mt = 0; mt < 4; ++mt) acc[mt] = (f32x4){0.f, 0.f, 0.f, 0.f};
    #pragma unroll
    for (int ks = 0; ks < 8; ++ks) {
      #pragma unroll
      for (int mt = 0; mt < 4; ++mt) {
        const int r = mt * 16 + cl;
        const int kb = (ks * 64 + krow * 2) ^ ((r & 7) << 4);
        const short8 af = *(const short8*)(lds + r * 512 + kb);
        acc[mt] = __builtin_amdgcn_mfma_f32_16x16x32_bf16(af, wf[ks], acc[mt], 0, 0, 0);
      }
    }
    // epilogue: bias + relu via LDS bounce -> full-cache-line stores
    const float bv = bias[d0];
    #pragma unroll
    for (int mt = 0; mt < 4; ++mt) {
      __syncthreads();
      #pragma unroll
      for (int q = 0; q < 4; ++q) {
        const int row16 = (lane >> 4) * 4 + q;   // C/D: col=lane&15, row=(lane>>4)*4+q
        const float v = acc[mt][q] + rsl[mt * 16 + row16] * bv;
        bnc[row16 * 132 + w * 16 + cl] = fmaxf(v, 0.f);
      }
      __syncthreads();
      const int rowg = 2 * w + (lane >> 5);
      const int colf = (lane & 31) * 4;
      const int n = n0 + mt * 16 + rowg;
      if (n < NND)
        *(f32x4*)(out + ((size_t)bt * NND + n) * 256 + dt * 128 + colf) =
            *(const f32x4*)(bnc + rowg * 132 + colf);
    }
  }
}

extern "C" void kernel_launch(void* const* d_in, const int* in_sizes, int n_in,
                              void* d_out, int out_size, void* d_ws, size_t ws_size,
                              hipStream_t stream) {
  const float* x  = (const float*)d_in[0];
  const float* Wm = (const float*)d_in[1];
  const float* b  = (const float*)d_in[2];
  const float* A  = (const float*)d_in[3];
  float* out = (float*)d_out;
  const int use_ws = (d_ws != nullptr && ws_size >= (size_t)WS_NEED) ? 1 : 0;
  if (use_ws) {
    prep_csr<<<(NROWP * 64 + 255) / 256, 256, 0, stream>>>(A, (char*)d_ws);
    prep_w<<<(16 * 8 * 64 + 255) / 256, 256, 0, stream>>>(Wm, (char*)d_ws);
  }
  gcn_main<<<GRID, 512, 0, stream>>>(x, Wm, b, A, out, (const char*)d_ws, use_ws);
}

// Round 6
// 46867.337 us; speedup vs baseline: 5.7850x; 5.7850x over previous
//
#include <hip/hip_runtime.h>
#include <hip/hip_bf16.h>

// GraphConvLayer: out = relu(A_norm @ (X@W + b))
// Reassociated: Y = A@X (sparse, ~22.5 nnz/row), out = relu(Y@W + rowsum(A)[n]*b[d])
// x: [1024,543,256] f32; W: [256,256] f32; b: [256]; A: [543,543] f32; out: [1024,543,256] f32
//
// R6 = R5 with two changes targeting the VGPR-cap/spill catastrophe:
//  1. __launch_bounds__(512, 2): every prior round used (..., 4) which produced a
//     64-VGPR cap (observed VGPR_Count=64 in ALL rounds) -> wholesale scratch spill.
//     With 2: cap >= 128 under either arg interpretation; LDS already limits to 2 blocks/CU.
//  2. gather de-lambda'd (no reference captures; static y[] indexing via unrolled rr).

#define NND    543
#define NROWP  640
#define RPB    64           // rows per block
#define NTILES 9            // blocks per bt
#define CH     64           // x chunk rows (f32 in LDS)
#define NCH    9
#define CAPR   64           // CSR slots per row (mean ~22.5)
#define BTOT   1024
#define GRID   (BTOT*NTILES)   // 9216, %8==0 -> bijective XCD swizzle

typedef __attribute__((ext_vector_type(8))) short short8;
typedef __attribute__((ext_vector_type(4))) float f32x4;

// ---- workspace (bytes) ----
#define WS_ENT 0                          // uint2[640][64] = 327680  {m, f32bits(a)}
#define WS_ST  327680                     // u16[640][12]: st[0..9] chunk offsets, [10] ovf flag
#define WS_RS  343040                     // f32[640] rowsum
#define WS_W   345600                     // bf16 frags [16][8][64][8] = 131072
#define WS_NEED 476672

// ---- LDS (bytes) ----
// [0,65536): x-chunk f32[64][256]; Y-swz bf16[64][512B] overlays [0,32768) after gather
#define L_BNC  65536                      // f32[16][132] = 8448 epilogue bounce
#define L_RS   73984                      // f32[64]
#define L_TOT  74240                      // 74.2KB -> 2 blocks/CU

__device__ __forceinline__ unsigned short f2bf(float f) {   // RNE f32 -> bf16 bits
  unsigned int u = __builtin_bit_cast(unsigned int, f);
  u += 0x7fffu + ((u >> 16) & 1u);
  return (unsigned short)(u >> 16);
}
__device__ __forceinline__ uint2 pack4(const f32x4 v) {
  uint2 u;
  u.x = (unsigned)f2bf(v.x) | ((unsigned)f2bf(v.y) << 16);
  u.y = (unsigned)f2bf(v.z) | ((unsigned)f2bf(v.w) << 16);
  return u;
}

// ---------------- prep: flat CSR + per-64-chunk offsets + rowsum (one wave/row) ----------------
__global__ void prep_csr(const float* __restrict__ A, char* __restrict__ ws) {
  const int wid = (blockIdx.x * blockDim.x + threadIdx.x) >> 6;
  const int lane = threadIdx.x & 63;
  if (wid >= NROWP) return;
  uint2* ep = (uint2*)(ws + WS_ENT) + (size_t)wid * CAPR;
  unsigned short* st = (unsigned short*)(ws + WS_ST) + wid * 12;
  float* rs = (float*)(ws + WS_RS);
  if (wid >= NND) {
    if (lane < 12) st[lane] = 0;
    if (lane == 0) rs[wid] = 0.f;
    return;
  }
  const float* arow = A + (size_t)wid * NND;
  float s = 0.f; int cnt = 0;
  for (int c = 0; c < NCH; ++c) {
    if (lane == 0) st[c] = (unsigned short)cnt;   // nnz with m < c*64
    const int m = c * 64 + lane;
    const float a = (m < NND) ? arow[m] : 0.f;
    s += a;
    const unsigned long long mask = __ballot(a != 0.f);
    if (a != 0.f) {
      const int idx = cnt + (int)__popcll(mask & ((1ull << lane) - 1ull));
      if (idx < CAPR) ep[idx] = make_uint2((unsigned)m, __builtin_bit_cast(unsigned, a));
    }
    cnt += (int)__popcll(mask);
  }
  #pragma unroll
  for (int o = 32; o > 0; o >>= 1) s += __shfl_xor(s, o);
  if (lane == 0) {
    st[9] = (unsigned short)cnt;
    st[10] = (cnt > CAPR) ? (unsigned short)1 : (unsigned short)0;
    st[11] = 0;
    rs[wid] = s;
  }
}

// ---------------- prep: W -> bf16 MFMA B-fragments [g][ks][lane][8] ----------------
__global__ void prep_w(const float* __restrict__ W, char* __restrict__ ws) {
  const int t = blockIdx.x * 256 + threadIdx.x;
  if (t >= 16 * 8 * 64) return;
  const int lane = t & 63, ks = (t >> 6) & 7, g = t >> 9;
  const int krow = (lane >> 4) * 8, col = g * 16 + (lane & 15);
  unsigned short* dst = (unsigned short*)(ws + WS_W) + (size_t)t * 8;
  #pragma unroll
  for (int e = 0; e < 8; e++) dst[e] = f2bf(W[(ks * 32 + krow + e) * 256 + col]);
}

// ---------------- main ----------------
__global__ __launch_bounds__(512, 2)   // cap >=128 VGPR either way; LDS 74KB -> 2 blocks/CU
void gcn_main(const float* __restrict__ x, const float* __restrict__ Wm,
              const float* __restrict__ bias, const float* __restrict__ A,
              float* __restrict__ out, const char* __restrict__ ws, int use_ws)
{
  __shared__ __align__(16) char lds[L_TOT];
  float* bnc = (float*)(lds + L_BNC);
  float* rsl = (float*)(lds + L_RS);

  const int tid = threadIdx.x;
  const int w = tid >> 6, lane = tid & 63;
  const int cl = lane & 15, krow = (lane >> 4) * 8;

  // XCD swizzle: the 9 tiles of one bt adjacent on one XCD, marching chunks in phase
  const int p = blockIdx.x;
  const int L = (p & 7) * (GRID / 8) + (p >> 3);
  const int bt = L / NTILES;
  const int tile = L - bt * NTILES;
  const int n0 = tile * RPB;

  const float* xbt = x + (size_t)bt * (NND * 256);
  const uint2* entp = (const uint2*)(ws + WS_ENT);
  const unsigned short* stp = (const unsigned short*)(ws + WS_ST);

  if (tid < RPB) rsl[tid] = use_ws ? ((const float*)(ws + WS_RS))[n0 + tid] : 0.f;

  // ---- gather: Y = A@X; x streamed once through LDS (f32, 9 chunks of 64 rows) ----
  f32x4 y[8];
  #pragma unroll
  for (int i = 0; i < 8; i++) y[i] = (f32x4){0.f, 0.f, 0.f, 0.f};

  for (int c = 0; c < NCH; ++c) {
    const int mbase = c * CH;
    const int rows = min(CH, NND - mbase);
    __syncthreads();                      // previous chunk's gather reads done
    #pragma unroll
    for (int k = 0; k < 8; ++k) {         // stage 64x256 f32, coalesced copy
      const int sl = tid + (k << 9);
      const int row = sl >> 6, f4 = sl & 63;
      if (row < rows)
        *(float4*)(lds + (row << 10) + (f4 << 4)) =
            *(const float4*)(xbt + ((size_t)(mbase + row) << 8) + (f4 << 2));
    }
    __syncthreads();

    #pragma unroll
    for (int rr = 0; rr < 8; ++rr) {      // de-lambda'd gather, y[rr] static index
      const int n = n0 + w * 8 + rr;
      const unsigned short* stn = stp + n * 12;
      if (use_ws && !stn[10]) {
        int j = stn[c];
        const int j1 = stn[c + 1];
        const uint2* ep = entp + (size_t)n * CAPR;
        for (; j + 1 < j1; j += 2) {
          const uint2 e0 = ep[j], e1 = ep[j + 1];
          const f32x4 x0 = *(const f32x4*)(lds + (((int)e0.x - mbase) << 10) + (lane << 4));
          const f32x4 x1 = *(const f32x4*)(lds + (((int)e1.x - mbase) << 10) + (lane << 4));
          y[rr] += __builtin_bit_cast(float, e0.y) * x0;
          y[rr] += __builtin_bit_cast(float, e1.y) * x1;
        }
        if (j < j1) {
          const uint2 e0 = ep[j];
          const f32x4 x0 = *(const f32x4*)(lds + (((int)e0.x - mbase) << 10) + (lane << 4));
          y[rr] += __builtin_bit_cast(float, e0.y) * x0;
        }
      } else if (n < NND) {               // overflow row or no-ws fallback: dense segment scan
        const float* arow = A + (size_t)n * NND + mbase;
        for (int m = 0; m < rows; ++m) {
          const float a = arow[m];
          if (a != 0.f) {
            const f32x4 xv = *(const f32x4*)(lds + (m << 10) + (lane << 4));
            y[rr] += a * xv;
          }
        }
      }
    }
  }

  if (!use_ws) {                          // fallback rowsums
    __syncthreads();
    for (int r = w; r < RPB; r += 8) {
      const int n = n0 + r;
      float s = 0.f;
      if (n < NND) for (int m = lane; m < NND; m += 64) s += A[(size_t)n * NND + m];
      #pragma unroll
      for (int o = 32; o > 0; o >>= 1) s += __shfl_xor(s, o);
      if (lane == 0) rsl[r] = s;
    }
  }

  // ---- Y -> LDS bf16 [64][256], XOR-swizzled (overlays dead x-chunk buffer) ----
  __syncthreads();
  #pragma unroll
  for (int rr = 0; rr < 8; ++rr) {
    const int r = w * 8 + rr;
    *(uint2*)(lds + r * 512 + ((lane * 8) ^ ((r & 7) << 4))) = pack4(y[rr]);
  }
  __syncthreads();

  // ---- MFMA: out_tile[64 x 256] = relu(Y@W + rs*b); wave w cols w*16 + dt*128 ----
  for (int dt = 0; dt < 2; ++dt) {
    const int d0 = dt * 128 + w * 16 + cl;
    short8 wf[8];
    if (use_ws) {
      const int g = dt * 8 + w;
      #pragma unroll
      for (int ks = 0; ks < 8; ++ks)
        wf[ks] = *(const short8*)(ws + WS_W + (size_t)(((g * 8 + ks) * 64 + lane) << 4));
    } else {
      #pragma unroll
      for (int ks = 0; ks < 8; ++ks) {
        #pragma unroll
        for (int e = 0; e < 8; ++e)
          wf[ks][e] = (short)f2bf(Wm[(ks * 32 + krow + e) * 256 + d0]);
      }
    }
    f32x4 acc[4];
    #pragma unroll
    for (int mt = 0; mt < 4; ++mt) acc[mt] = (f32x4){0.f, 0.f, 0.f, 0.f};
    #pragma unroll
    for (int ks = 0; ks < 8; ++ks) {
      #pragma unroll
      for (int mt = 0; mt < 4; ++mt) {
        const int r = mt * 16 + cl;
        const int kb = (ks * 64 + krow * 2) ^ ((r & 7) << 4);
        const short8 af = *(const short8*)(lds + r * 512 + kb);
        acc[mt] = __builtin_amdgcn_mfma_f32_16x16x32_bf16(af, wf[ks], acc[mt], 0, 0, 0);
      }
    }
    // epilogue: bias + relu via LDS bounce -> full-cache-line stores
    const float bv = bias[d0];
    #pragma unroll
    for (int mt = 0; mt < 4; ++mt) {
      __syncthreads();
      #pragma unroll
      for (int q = 0; q < 4; ++q) {
        const int row16 = (lane >> 4) * 4 + q;   // C/D: col=lane&15, row=(lane>>4)*4+q
        const float v = acc[mt][q] + rsl[mt * 16 + row16] * bv;
        bnc[row16 * 132 + w * 16 + cl] = fmaxf(v, 0.f);
      }
      __syncthreads();
      const int rowg = 2 * w + (lane >> 5);
      const int colf = (lane & 31) * 4;
      const int n = n0 + mt * 16 + rowg;
      if (n < NND)
        *(f32x4*)(out + ((size_t)bt * NND + n) * 256 + dt * 128 + colf) =
            *(const f32x4*)(bnc + rowg * 132 + colf);
    }
  }
}

extern "C" void kernel_launch(void* const* d_in, const int* in_sizes, int n_in,
                              void* d_out, int out_size, void* d_ws, size_t ws_size,
                              hipStream_t stream) {
  const float* x  = (const float*)d_in[0];
  const float* Wm = (const float*)d_in[1];
  const float* b  = (const float*)d_in[2];
  const float* A  = (const float*)d_in[3];
  float* out = (float*)d_out;
  const int use_ws = (d_ws != nullptr && ws_size >= (size_t)WS_NEED) ? 1 : 0;
  if (use_ws) {
    prep_csr<<<(NROWP * 64 + 255) / 256, 256, 0, stream>>>(A, (char*)d_ws);
    prep_w<<<(16 * 8 * 64 + 255) / 256, 256, 0, stream>>>(Wm, (char*)d_ws);
  }
  gcn_main<<<GRID, 512, 0, stream>>>(x, Wm, b, A, out, (const char*)d_ws, use_ws);
}

// Round 7
// 1187.721 us; speedup vs baseline: 228.2747x; 39.4599x over previous
//
#include <hip/hip_runtime.h>
#include <hip/hip_bf16.h>

// GraphConvLayer: out = relu(A_norm @ (X@W + b))
// Reassociated: Y = A@X (sparse, ~22.5 nnz/row), out = relu(Y@W + rowsum(A)[n]*b[d])
// x: [1024,543,256] f32; W: [256,256] f32; b: [256]; A: [543,543] f32; out: [1024,543,256] f32
//
// R7: register-minimal fused kernel. Gather: one row at a time, single named f32x4
// accumulator, x read directly from global (L2-served, ~2.65x reuse per block).
// No staging pipeline, no persistent Y registers -> nothing for the allocator to spill.
// MFMA on bf16 Y in XOR-swizzled LDS; epilogue bounces 16x32 tiles through per-wave
// LDS -> full 128B-line dwordx4 stores. All register arrays statically indexed.

#define NND    543
#define NROWP  640
#define RPB    64           // rows per block
#define NTILES 9            // blocks per bt
#define CAPR   64           // CSR slots per row (mean ~22.5, +9 sigma)
#define BTOT   1024
#define GRID   (BTOT*NTILES)   // 9216, %8==0 -> bijective XCD swizzle

typedef __attribute__((ext_vector_type(8))) short short8;
typedef __attribute__((ext_vector_type(4))) float f32x4;

// ---- workspace (bytes) ----
#define WS_ENT 0                          // uint2[640][64] = 327680  {m, f32bits(a)}
#define WS_CNT 327680                     // u32[640]: padded-to-4 count, or ~0 = overflow
#define WS_RS  330240                     // f32[640] rowsum
#define WS_W   332800                     // bf16 frags [16][8][64][8] = 131072
#define WS_NEED 463872

// ---- LDS (bytes) ----
#define L_Y    0                          // Y bf16 [64 rows][512B], XOR-swizzled = 32768
#define L_BNC  32768                      // per-wave bounce: 4 * 16*36*4 = 9216
#define L_RS   41984                      // f32[64]
#define L_TOT  42240                      // 42.2 KB -> 3 blocks/CU

__device__ __forceinline__ unsigned short f2bf(float f) {   // RNE f32 -> bf16 bits
  unsigned int u = __builtin_bit_cast(unsigned int, f);
  u += 0x7fffu + ((u >> 16) & 1u);
  return (unsigned short)(u >> 16);
}
__device__ __forceinline__ uint2 pack4(const f32x4 v) {
  uint2 u;
  u.x = (unsigned)f2bf(v.x) | ((unsigned)f2bf(v.y) << 16);
  u.y = (unsigned)f2bf(v.z) | ((unsigned)f2bf(v.w) << 16);
  return u;
}

// ---------------- prep: flat padded CSR + rowsum (one wave per row) ----------------
__global__ void prep_csr(const float* __restrict__ A, char* __restrict__ ws) {
  const int wid = (blockIdx.x * blockDim.x + threadIdx.x) >> 6;
  const int lane = threadIdx.x & 63;
  if (wid >= NROWP) return;
  uint2* ep = (uint2*)(ws + WS_ENT) + (size_t)wid * CAPR;
  unsigned* cw = (unsigned*)(ws + WS_CNT);
  float* rs = (float*)(ws + WS_RS);
  if (wid >= NND) {
    if (lane == 0) { cw[wid] = 0u; rs[wid] = 0.f; }
    return;
  }
  const float* arow = A + (size_t)wid * NND;
  float s = 0.f; int cnt = 0;
  for (int m0 = 0; m0 < NND; m0 += 64) {
    const int m = m0 + lane;
    const float a = (m < NND) ? arow[m] : 0.f;
    s += a;
    const unsigned long long mask = __ballot(a != 0.f);
    if (a != 0.f) {
      const int idx = cnt + (int)__popcll(mask & ((1ull << lane) - 1ull));
      if (idx < CAPR) ep[idx] = make_uint2((unsigned)m, __builtin_bit_cast(unsigned, a));
    }
    cnt += (int)__popcll(mask);
  }
  #pragma unroll
  for (int o = 32; o > 0; o >>= 1) s += __shfl_xor(s, o);
  const int cpad = (cnt + 3) & ~3;
  if (cnt <= CAPR && lane < cpad - cnt) ep[cnt + lane] = make_uint2(0u, 0u);  // a=0 pad
  if (lane == 0) {
    cw[wid] = (cnt <= CAPR) ? (unsigned)cpad : 0xFFFFFFFFu;
    rs[wid] = s;
  }
}

// ---------------- prep: W -> bf16 MFMA B-fragments [g][ks][lane][8], g = col/16 ----------------
__global__ void prep_w(const float* __restrict__ W, char* __restrict__ ws) {
  const int t = blockIdx.x * 256 + threadIdx.x;
  if (t >= 16 * 8 * 64) return;
  const int lane = t & 63, ks = (t >> 6) & 7, g = t >> 9;
  const int krow = (lane >> 4) * 8, col = g * 16 + (lane & 15);
  unsigned short* dst = (unsigned short*)(ws + WS_W) + (size_t)t * 8;
  #pragma unroll
  for (int e = 0; e < 8; e++) dst[e] = f2bf(W[(ks * 32 + krow + e) * 256 + col]);
}

// ---------------- main ----------------
__global__ __launch_bounds__(256, 2)   // generous VGPR cap; LDS 42KB -> 3 blocks/CU
void gcn_main(const float* __restrict__ x, const float* __restrict__ Wm,
              const float* __restrict__ bias, const float* __restrict__ A,
              float* __restrict__ out, const char* __restrict__ ws, int use_ws)
{
  __shared__ __align__(16) char lds[L_TOT];
  float* rsl = (float*)(lds + L_RS);

  const int tid = threadIdx.x;
  const int w = tid >> 6, lane = tid & 63;
  const int cl = lane & 15, krow = (lane >> 4) * 8;

  // XCD swizzle: consecutive L (tiles of one bt) co-resident on one XCD
  const int p = blockIdx.x;
  const int L = (p & 7) * (GRID / 8) + (p >> 3);
  const int bt = L / NTILES;
  const int tile = L - bt * NTILES;
  const int n0 = tile * RPB;

  const float* xbt = x + (size_t)bt * (NND * 256);
  const uint2* entp = (const uint2*)(ws + WS_ENT);
  const unsigned* cnts = (const unsigned*)(ws + WS_CNT);

  if (tid < RPB) rsl[tid] = use_ws ? ((const float*)(ws + WS_RS))[n0 + tid] : 0.f;

  // ---- gather: one row at a time, single f32x4 accumulator, x direct from global ----
  for (int rr = 0; rr < 16; ++rr) {
    const int r = w * 16 + rr;
    const int n = n0 + r;
    f32x4 yv = (f32x4){0.f, 0.f, 0.f, 0.f};
    bool dense = !use_ws;

    if (use_ws) {
      const unsigned cnt = cnts[n];
      if (cnt <= CAPR) {
        const uint2* ep = entp + (size_t)n * CAPR;
        for (unsigned j = 0; j < cnt; j += 4) {          // cnt padded to multiple of 4
          const uint2 e0 = ep[j], e1 = ep[j + 1], e2 = ep[j + 2], e3 = ep[j + 3];
          const f32x4 x0 = *(const f32x4*)(xbt + (e0.x << 8) + (lane << 2));
          const f32x4 x1 = *(const f32x4*)(xbt + (e1.x << 8) + (lane << 2));
          const f32x4 x2 = *(const f32x4*)(xbt + (e2.x << 8) + (lane << 2));
          const f32x4 x3 = *(const f32x4*)(xbt + (e3.x << 8) + (lane << 2));
          yv += __builtin_bit_cast(float, e0.y) * x0;
          yv += __builtin_bit_cast(float, e1.y) * x1;
          yv += __builtin_bit_cast(float, e2.y) * x2;
          yv += __builtin_bit_cast(float, e3.y) * x3;
        }
      } else {
        dense = true;                                    // overflow row
      }
    }
    if (dense && n < NND) {                              // overflow or no-ws fallback
      const float* arow = A + (size_t)n * NND;
      float s = 0.f;
      for (int m = 0; m < NND; ++m) {
        const float a = arow[m];
        s += a;
        if (a != 0.f) {
          const f32x4 xv = *(const f32x4*)(xbt + (m << 8) + (lane << 2));
          yv += a * xv;
        }
      }
      if (!use_ws && lane == 0) rsl[r] = s;
    }
    // Y row -> LDS bf16, XOR-swizzled
    *(uint2*)(lds + r * 512 + ((lane * 8) ^ ((r & 7) << 4))) = pack4(yv);
  }
  __syncthreads();

  // ---- MFMA + epilogue: wave w owns cols [w*64, w*64+64), two 32-col pairs ----
  float* wb = (float*)(lds + L_BNC) + w * (16 * 36);     // private 16x32 bounce, stride 36

  for (int pair = 0; pair < 2; ++pair) {
    const int gA = w * 4 + pair * 2;                     // col group for dt=0 of pair
    short8 wf[8];
    f32x4 accA[4], accB[4];

    // dt = 0 of pair
    if (use_ws) {
      #pragma unroll
      for (int ks = 0; ks < 8; ++ks)
        wf[ks] = *(const short8*)(ws + WS_W + (size_t)(((gA * 8 + ks) * 64 + lane) << 4));
    } else {
      #pragma unroll
      for (int ks = 0; ks < 8; ++ks) {
        #pragma unroll
        for (int e = 0; e < 8; ++e)
          wf[ks][e] = (short)f2bf(Wm[(ks * 32 + krow + e) * 256 + gA * 16 + cl]);
      }
    }
    #pragma unroll
    for (int mt = 0; mt < 4; ++mt) accA[mt] = (f32x4){0.f, 0.f, 0.f, 0.f};
    #pragma unroll
    for (int ks = 0; ks < 8; ++ks) {
      #pragma unroll
      for (int mt = 0; mt < 4; ++mt) {
        const int r = mt * 16 + cl;
        const int kb = (ks * 64 + krow * 2) ^ ((r & 7) << 4);
        const short8 af = *(const short8*)(lds + r * 512 + kb);
        accA[mt] = __builtin_amdgcn_mfma_f32_16x16x32_bf16(af, wf[ks], accA[mt], 0, 0, 0);
      }
    }
    // dt = 1 of pair (reuse wf storage)
    if (use_ws) {
      #pragma unroll
      for (int ks = 0; ks < 8; ++ks)
        wf[ks] = *(const short8*)(ws + WS_W + (size_t)((((gA + 1) * 8 + ks) * 64 + lane) << 4));
    } else {
      #pragma unroll
      for (int ks = 0; ks < 8; ++ks) {
        #pragma unroll
        for (int e = 0; e < 8; ++e)
          wf[ks][e] = (short)f2bf(Wm[(ks * 32 + krow + e) * 256 + (gA + 1) * 16 + cl]);
      }
    }
    #pragma unroll
    for (int mt = 0; mt < 4; ++mt) accB[mt] = (f32x4){0.f, 0.f, 0.f, 0.f};
    #pragma unroll
    for (int ks = 0; ks < 8; ++ks) {
      #pragma unroll
      for (int mt = 0; mt < 4; ++mt) {
        const int r = mt * 16 + cl;
        const int kb = (ks * 64 + krow * 2) ^ ((r & 7) << 4);
        const short8 af = *(const short8*)(lds + r * 512 + kb);
        accB[mt] = __builtin_amdgcn_mfma_f32_16x16x32_bf16(af, wf[ks], accB[mt], 0, 0, 0);
      }
    }

    // epilogue: bias + relu -> per-wave bounce -> full-line dwordx4 stores
    const int dA = w * 64 + pair * 32 + cl;
    const float bvA = bias[dA], bvB = bias[dA + 16];
    #pragma unroll
    for (int mt = 0; mt < 4; ++mt) {
      #pragma unroll
      for (int q = 0; q < 4; ++q) {
        const int r16 = (lane >> 4) * 4 + q;             // C/D: col=lane&15, row=(lane>>4)*4+q
        const float rsv = rsl[mt * 16 + r16];
        wb[r16 * 36 + cl]      = fmaxf(accA[mt][q] + rsv * bvA, 0.f);
        wb[r16 * 36 + 16 + cl] = fmaxf(accB[mt][q] + rsv * bvB, 0.f);
      }
      asm volatile("s_waitcnt lgkmcnt(0)" ::: "memory"); // wave-lockstep: writes visible
      #pragma unroll
      for (int v = 0; v < 2; ++v) {
        const int i = lane * 2 + v;                      // 0..127 vec4 slots of 16x32 tile
        const int r = i >> 3, cv = i & 7;
        const int n = n0 + mt * 16 + r;
        if (n < NND)
          *(f32x4*)(out + ((size_t)bt * NND + n) * 256 + w * 64 + pair * 32 + cv * 4) =
              *(const f32x4*)(wb + r * 36 + cv * 4);
      }
    }
  }
}

extern "C" void kernel_launch(void* const* d_in, const int* in_sizes, int n_in,
                              void* d_out, int out_size, void* d_ws, size_t ws_size,
                              hipStream_t stream) {
  const float* x  = (const float*)d_in[0];
  const float* Wm = (const float*)d_in[1];
  const float* b  = (const float*)d_in[2];
  const float* A  = (const float*)d_in[3];
  float* out = (float*)d_out;
  const int use_ws = (d_ws != nullptr && ws_size >= (size_t)WS_NEED) ? 1 : 0;
  if (use_ws) {
    prep_csr<<<(NROWP * 64 + 255) / 256, 256, 0, stream>>>(A, (char*)d_ws);
    prep_w<<<(16 * 8 * 64 + 255) / 256, 256, 0, stream>>>(Wm, (char*)d_ws);
  }
  gcn_main<<<GRID, 256, 0, stream>>>(x, Wm, b, A, out, (const char*)d_ws, use_ws);
}

// Round 8
// 690.955 us; speedup vs baseline: 392.3938x; 1.7190x over previous
//
#include <hip/hip_runtime.h>
#include <hip/hip_bf16.h>

// GraphConvLayer: out = relu(A_norm @ (X@W + b))
// Reassociated: Y = A@X (sparse, ~22.5 nnz/row), out = relu(Y@W + rowsum(A)[n]*b[d])
// x: [1024,543,256] f32; W: [256,256] f32; b: [256]; A: [543,543] f32; out: [1024,543,256] f32
//
// R8 = R7 (traffic-ideal, no spill) + latency-regime fixes:
//  - 512 thr/block, 8 rows/wave (serial chain halved), 16 waves/CU
//  - 2-row ILP gather: 8 x-loads in flight per iteration
//  - CSR rows zero-padded to CAPR so row pairs iterate uniformly
//  - wave-uniform (readfirstlane) entry addressing -> scalar loads

#define NND    543
#define NROWP  640
#define RPB    64           // rows per block
#define NTILES 9            // blocks per bt
#define CAPR   64           // CSR slots per row (mean ~22.5, +9 sigma)
#define BTOT   1024
#define GRID   (BTOT*NTILES)   // 9216, %8==0 -> bijective XCD swizzle

typedef __attribute__((ext_vector_type(8))) short short8;
typedef __attribute__((ext_vector_type(4))) float f32x4;

// ---- workspace (bytes) ----
#define WS_ENT 0                          // uint2[640][64] = 327680 {m, f32bits(a)}, zero-padded
#define WS_CNT 327680                     // u32[640]: count (<=CAPR) or ~0 = overflow
#define WS_RS  330240                     // f32[640] rowsum
#define WS_W   332800                     // bf16 frags [16][8][64][8] = 131072
#define WS_NEED 463872

// ---- LDS (bytes) ----
#define L_Y    0                          // Y bf16 [64 rows][512B], XOR-swizzled = 32768
#define L_BNC  32768                      // per-wave bounce: 8 * 16*36*4 = 18432
#define L_RS   51200                      // f32[64]
#define L_TOT  51456                      // 50.2 KB

__device__ __forceinline__ unsigned short f2bf(float f) {   // RNE f32 -> bf16 bits
  unsigned int u = __builtin_bit_cast(unsigned int, f);
  u += 0x7fffu + ((u >> 16) & 1u);
  return (unsigned short)(u >> 16);
}
__device__ __forceinline__ uint2 pack4(const f32x4 v) {
  uint2 u;
  u.x = (unsigned)f2bf(v.x) | ((unsigned)f2bf(v.y) << 16);
  u.y = (unsigned)f2bf(v.z) | ((unsigned)f2bf(v.w) << 16);
  return u;
}

// ---------------- prep: flat CSR zero-padded to CAPR + rowsum (one wave/row) ----------------
__global__ void prep_csr(const float* __restrict__ A, char* __restrict__ ws) {
  const int wid = (blockIdx.x * blockDim.x + threadIdx.x) >> 6;
  const int lane = threadIdx.x & 63;
  if (wid >= NROWP) return;
  uint2* ep = (uint2*)(ws + WS_ENT) + (size_t)wid * CAPR;
  unsigned* cw = (unsigned*)(ws + WS_CNT);
  float* rs = (float*)(ws + WS_RS);
  if (wid >= NND) {
    for (int k = lane; k < CAPR; k += 64) ep[k] = make_uint2(0u, 0u);
    if (lane == 0) { cw[wid] = 0u; rs[wid] = 0.f; }
    return;
  }
  const float* arow = A + (size_t)wid * NND;
  float s = 0.f; int cnt = 0;
  for (int m0 = 0; m0 < NND; m0 += 64) {
    const int m = m0 + lane;
    const float a = (m < NND) ? arow[m] : 0.f;
    s += a;
    const unsigned long long mask = __ballot(a != 0.f);
    if (a != 0.f) {
      const int idx = cnt + (int)__popcll(mask & ((1ull << lane) - 1ull));
      if (idx < CAPR) ep[idx] = make_uint2((unsigned)m, __builtin_bit_cast(unsigned, a));
    }
    cnt += (int)__popcll(mask);
  }
  #pragma unroll
  for (int o = 32; o > 0; o >>= 1) s += __shfl_xor(s, o);
  if (cnt <= CAPR) {                       // zero-pad rest of row: {m=0, a=0} is harmless
    for (int k = cnt + lane; k < CAPR; k += 64) ep[k] = make_uint2(0u, 0u);
  }
  if (lane == 0) {
    cw[wid] = (cnt <= CAPR) ? (unsigned)((cnt + 3) & ~3) : 0xFFFFFFFFu;
    rs[wid] = s;
  }
}

// ---------------- prep: W -> bf16 MFMA B-fragments [g][ks][lane][8], g = col/16 ----------------
__global__ void prep_w(const float* __restrict__ W, char* __restrict__ ws) {
  const int t = blockIdx.x * 256 + threadIdx.x;
  if (t >= 16 * 8 * 64) return;
  const int lane = t & 63, ks = (t >> 6) & 7, g = t >> 9;
  const int krow = (lane >> 4) * 8, col = g * 16 + (lane & 15);
  unsigned short* dst = (unsigned short*)(ws + WS_W) + (size_t)t * 8;
  #pragma unroll
  for (int e = 0; e < 8; e++) dst[e] = f2bf(W[(ks * 32 + krow + e) * 256 + col]);
}

__device__ __forceinline__ void dense_row(const float* __restrict__ A,
                                          const float* __restrict__ xbt,
                                          const int n, const int lane, f32x4& yv) {
  const float* arow = A + (size_t)n * NND;
  for (int m = 0; m < NND; ++m) {
    const float a = arow[m];
    if (a != 0.f) {
      const f32x4 xv = *(const f32x4*)(xbt + (m << 8) + (lane << 2));
      yv += a * xv;
    }
  }
}

// ---------------- main ----------------
__global__ __launch_bounds__(512, 2)   // 2 blocks/CU min -> 128 VGPR cap (empirical rule)
void gcn_main(const float* __restrict__ x, const float* __restrict__ Wm,
              const float* __restrict__ bias, const float* __restrict__ A,
              float* __restrict__ out, const char* __restrict__ ws, int use_ws)
{
  __shared__ __align__(16) char lds[L_TOT];
  float* rsl = (float*)(lds + L_RS);

  const int tid = threadIdx.x;
  const int w = tid >> 6, lane = tid & 63;
  const int cl = lane & 15, krow = (lane >> 4) * 8;

  // XCD swizzle: consecutive L (tiles of one bt) co-resident on one XCD
  const int p = blockIdx.x;
  const int L = (p & 7) * (GRID / 8) + (p >> 3);
  const int bt = L / NTILES;
  const int tile = L - bt * NTILES;
  const int n0 = tile * RPB;

  const float* xbt = x + (size_t)bt * (NND * 256);
  const uint2* entp = (const uint2*)(ws + WS_ENT);
  const unsigned* cnts = (const unsigned*)(ws + WS_CNT);

  if (tid < RPB) rsl[tid] = use_ws ? ((const float*)(ws + WS_RS))[n0 + tid] : 0.f;

  // ---- gather: 2 rows in flight, 8 x-loads/iter, scalar entry loads ----
  for (int rr = 0; rr < 8; rr += 2) {
    const int r0 = w * 8 + rr;
    const int nA = __builtin_amdgcn_readfirstlane(n0 + r0);      // wave-uniform
    const int nB = nA + 1;
    f32x4 yA = (f32x4){0.f, 0.f, 0.f, 0.f};
    f32x4 yB = (f32x4){0.f, 0.f, 0.f, 0.f};

    if (use_ws) {
      const unsigned cA = cnts[nA], cB = cnts[nB];
      if (cA <= CAPR && cB <= CAPR) {
        const unsigned cm = cA > cB ? cA : cB;                   // rows zero-padded -> safe
        const uint2* epA = entp + (size_t)nA * CAPR;
        const uint2* epB = entp + (size_t)nB * CAPR;
        for (unsigned j = 0; j < cm; j += 4) {
          const uint2 a0 = epA[j], a1 = epA[j+1], a2 = epA[j+2], a3 = epA[j+3];
          const uint2 b0 = epB[j], b1 = epB[j+1], b2 = epB[j+2], b3 = epB[j+3];
          const f32x4 xa0 = *(const f32x4*)(xbt + (a0.x << 8) + (lane << 2));
          const f32x4 xa1 = *(const f32x4*)(xbt + (a1.x << 8) + (lane << 2));
          const f32x4 xa2 = *(const f32x4*)(xbt + (a2.x << 8) + (lane << 2));
          const f32x4 xa3 = *(const f32x4*)(xbt + (a3.x << 8) + (lane << 2));
          const f32x4 xb0 = *(const f32x4*)(xbt + (b0.x << 8) + (lane << 2));
          const f32x4 xb1 = *(const f32x4*)(xbt + (b1.x << 8) + (lane << 2));
          const f32x4 xb2 = *(const f32x4*)(xbt + (b2.x << 8) + (lane << 2));
          const f32x4 xb3 = *(const f32x4*)(xbt + (b3.x << 8) + (lane << 2));
          yA += __builtin_bit_cast(float, a0.y) * xa0;
          yA += __builtin_bit_cast(float, a1.y) * xa1;
          yA += __builtin_bit_cast(float, a2.y) * xa2;
          yA += __builtin_bit_cast(float, a3.y) * xa3;
          yB += __builtin_bit_cast(float, b0.y) * xb0;
          yB += __builtin_bit_cast(float, b1.y) * xb1;
          yB += __builtin_bit_cast(float, b2.y) * xb2;
          yB += __builtin_bit_cast(float, b3.y) * xb3;
        }
      } else {                                                   // rare overflow rows
        if (cA <= CAPR) {
          const uint2* epA = entp + (size_t)nA * CAPR;
          for (unsigned j = 0; j < cA; ++j) {
            const uint2 e = epA[j];
            yA += __builtin_bit_cast(float, e.y) *
                  *(const f32x4*)(xbt + (e.x << 8) + (lane << 2));
          }
        } else if (nA < NND) dense_row(A, xbt, nA, lane, yA);
        if (cB <= CAPR) {
          const uint2* epB = entp + (size_t)nB * CAPR;
          for (unsigned j = 0; j < cB; ++j) {
            const uint2 e = epB[j];
            yB += __builtin_bit_cast(float, e.y) *
                  *(const f32x4*)(xbt + (e.x << 8) + (lane << 2));
          }
        } else if (nB < NND) dense_row(A, xbt, nB, lane, yB);
      }
    } else {                                                     // no-ws fallback
      if (nA < NND) {
        const float* arow = A + (size_t)nA * NND;
        float s = 0.f;
        for (int m = 0; m < NND; ++m) {
          const float a = arow[m];
          s += a;
          if (a != 0.f) yA += a * *(const f32x4*)(xbt + (m << 8) + (lane << 2));
        }
        if (lane == 0) rsl[r0] = s;
      }
      if (nB < NND) {
        const float* arow = A + (size_t)nB * NND;
        float s = 0.f;
        for (int m = 0; m < NND; ++m) {
          const float a = arow[m];
          s += a;
          if (a != 0.f) yB += a * *(const f32x4*)(xbt + (m << 8) + (lane << 2));
        }
        if (lane == 0) rsl[r0 + 1] = s;
      }
    }

    // Y rows -> LDS bf16, XOR-swizzled
    *(uint2*)(lds + r0 * 512       + ((lane * 8) ^ ((r0 & 7) << 4)))       = pack4(yA);
    *(uint2*)(lds + (r0+1) * 512   + ((lane * 8) ^ (((r0+1) & 7) << 4)))   = pack4(yB);
  }
  __syncthreads();

  // ---- MFMA: wave w owns cols [w*32, w*32+32): groups gA=2w (cols 0-15), gB=2w+1 ----
  const int gA = 2 * w;
  short8 wfA[8], wfB[8];
  if (use_ws) {
    #pragma unroll
    for (int ks = 0; ks < 8; ++ks) {
      wfA[ks] = *(const short8*)(ws + WS_W + (size_t)(((gA * 8 + ks) * 64 + lane) << 4));
      wfB[ks] = *(const short8*)(ws + WS_W + (size_t)((((gA + 1) * 8 + ks) * 64 + lane) << 4));
    }
  } else {
    #pragma unroll
    for (int ks = 0; ks < 8; ++ks) {
      #pragma unroll
      for (int e = 0; e < 8; ++e) {
        wfA[ks][e] = (short)f2bf(Wm[(ks * 32 + krow + e) * 256 + gA * 16 + cl]);
        wfB[ks][e] = (short)f2bf(Wm[(ks * 32 + krow + e) * 256 + (gA + 1) * 16 + cl]);
      }
    }
  }
  f32x4 accA[4], accB[4];
  #pragma unroll
  for (int mt = 0; mt < 4; ++mt) {
    accA[mt] = (f32x4){0.f, 0.f, 0.f, 0.f};
    accB[mt] = (f32x4){0.f, 0.f, 0.f, 0.f};
  }
  #pragma unroll
  for (int ks = 0; ks < 8; ++ks) {
    #pragma unroll
    for (int mt = 0; mt < 4; ++mt) {
      const int r = mt * 16 + cl;
      const int kb = (ks * 64 + krow * 2) ^ ((r & 7) << 4);
      const short8 af = *(const short8*)(lds + r * 512 + kb);
      accA[mt] = __builtin_amdgcn_mfma_f32_16x16x32_bf16(af, wfA[ks], accA[mt], 0, 0, 0);
      accB[mt] = __builtin_amdgcn_mfma_f32_16x16x32_bf16(af, wfB[ks], accB[mt], 0, 0, 0);
    }
  }

  // ---- epilogue: bias + relu -> per-wave bounce -> full 128B-line dwordx4 stores ----
  float* wb = (float*)(lds + L_BNC) + w * (16 * 36);
  const int dA = w * 32 + cl;
  const float bvA = bias[dA], bvB = bias[dA + 16];
  #pragma unroll
  for (int mt = 0; mt < 4; ++mt) {
    #pragma unroll
    for (int q = 0; q < 4; ++q) {
      const int r16 = (lane >> 4) * 4 + q;               // C/D: col=lane&15, row=(lane>>4)*4+q
      const float rsv = rsl[mt * 16 + r16];
      wb[r16 * 36 + cl]      = fmaxf(accA[mt][q] + rsv * bvA, 0.f);
      wb[r16 * 36 + 16 + cl] = fmaxf(accB[mt][q] + rsv * bvB, 0.f);
    }
    asm volatile("s_waitcnt lgkmcnt(0)" ::: "memory");   // wave-lockstep write visibility
    #pragma unroll
    for (int v = 0; v < 2; ++v) {
      const int i = lane * 2 + v;                        // 128 vec4 slots of 16x32 tile
      const int rI = i >> 3, cv = i & 7;
      const int n = n0 + mt * 16 + rI;
      if (n < NND)
        *(f32x4*)(out + ((size_t)bt * NND + n) * 256 + w * 32 + cv * 4) =
            *(const f32x4*)(wb + rI * 36 + cv * 4);
    }
  }
}

extern "C" void kernel_launch(void* const* d_in, const int* in_sizes, int n_in,
                              void* d_out, int out_size, void* d_ws, size_t ws_size,
                              hipStream_t stream) {
  const float* x  = (const float*)d_in[0];
  const float* Wm = (const float*)d_in[1];
  const float* b  = (const float*)d_in[2];
  const float* A  = (const float*)d_in[3];
  float* out = (float*)d_out;
  const int use_ws = (d_ws != nullptr && ws_size >= (size_t)WS_NEED) ? 1 : 0;
  if (use_ws) {
    prep_csr<<<(NROWP * 64 + 255) / 256, 256, 0, stream>>>(A, (char*)d_ws);
    prep_w<<<(16 * 8 * 64 + 255) / 256, 256, 0, stream>>>(Wm, (char*)d_ws);
  }
  gcn_main<<<GRID, 512, 0, stream>>>(x, Wm, b, A, out, (const char*)d_ws, use_ws);
}